// Round 1
// baseline (589.865 us; speedup 1.0000x reference)
//
#include <hip/hip_runtime.h>

#define NETSZ 512
#define DIMIN 513
#define BB 256
#define TT 300

__device__ __forceinline__ float wred(float v) {
#pragma unroll
    for (int off = 32; off >= 1; off >>= 1)
        v += __shfl_xor(v, off, 64);
    return v;
}

// retanh(x) = max(tanh(x), 0); exact for x<=0, fast exp/rcp path for x>0.
// Large x: __expf -> inf, rcp(inf)=0 -> t=1 (correct saturation).
__device__ __forceinline__ float retanh_fast(float x) {
    float e = __expf(2.0f * x);
    float t = 1.0f - 2.0f * __builtin_amdgcn_rcpf(e + 1.0f);
    return x > 0.0f ? t : 0.0f;
}

__global__ __launch_bounds__(512) void rnn_fused(
    const float* __restrict__ input,
    const float* __restrict__ noise,
    const float* __restrict__ top,
    const float* __restrict__ why,
    float* __restrict__ outp_base,
    float* __restrict__ hstore)
{
    const int b = blockIdx.x;
    const int r = threadIdx.x;
    const int wid = r >> 6;
    const int lane = r & 63;

    __shared__ float lds[2][8][6];   // double-buffered cross-wave partials

    const float tp0 = top[0];
    const float tp1 = top[1];

    float s, c;
    sincosf((float)r * (6.2831853071795864769f / 512.0f), &s, &c);
    const float w0 = why[r];
    const float w1 = why[NETSZ + r];

    const float* inp = input + (size_t)b * TT * DIMIN + r;
    const float* nzp = noise + (size_t)b * TT * NETSZ + r;
    float*       hsp = hstore + (size_t)b * TT * NETSZ + r;
    float*       outp = outp_base + (size_t)b * TT * 2;

    // --- prologue: load in_0, prefetch rings (noise t=0..2, input t=1..3) ---
    float in0v = inp[0];
    float n0 = nzp[0];
    float n1 = nzp[(size_t)1 * NETSZ];
    float n2 = nzp[(size_t)2 * NETSZ];
    float i1 = inp[(size_t)1 * DIMIN];   // holds in_{t+1} for t%3==0
    float i2 = inp[(size_t)2 * DIMIN];   // holds in_{t+1} for t%3==1
    float i0 = inp[(size_t)3 * DIMIN];   // holds in_{t+1} for t%3==2

    // reduce u_0 = in_0·c, v_0 = in_0·s  (uses parity-1 buffer)
    float rU0 = wred(in0v * c);
    float rV0 = wred(in0v * s);
    if (lane == 0) { lds[1][wid][4] = rU0; lds[1][wid][5] = rV0; }
    __syncthreads();
    float U = 0.f, V = 0.f;
#pragma unroll
    for (int w = 0; w < 8; ++w) { U += lds[1][w][4]; V += lds[1][w][5]; }

    float P = 0.f, Q = 0.f, ah = 0.f;   // h0 = retanh(0) = 0 -> P=Q=0

    // Per step t: consume nz_t (slot t%3) and in_{t+1} (slot (t+1)%3);
    // prefetch nz_{t+3} / in_{t+4} into the same slots (3-step-latency cover).
#define STEP(TI, NZ, IN)                                                        \
    {                                                                           \
        const int t_ = (TI);                                                    \
        float coefC = tp0 * (P + U);                                            \
        float coefS = tp0 * (Q + V);                                            \
        ah = 0.9f * ah + 0.1f * (coefC * c + coefS * s + tp1);                  \
        float hv = retanh_fast(ah) + NZ;                                        \
        hsp[(size_t)t_ * NETSZ] = hv;                                           \
        int tn = t_ + 3; if (tn > TT - 1) tn = TT - 1;                          \
        NZ = nzp[(size_t)tn * NETSZ];                                           \
        float inn = IN;                                                         \
        int tm = t_ + 4; if (tm > TT - 1) tm = TT - 1;                          \
        IN = inp[(size_t)tm * DIMIN];                                           \
        float rP = wred(hv * c);                                                \
        float rQ = wred(hv * s);                                                \
        float r0 = wred(hv * w0);                                               \
        float r1 = wred(hv * w1);                                               \
        float rU = wred(inn * c);                                               \
        float rV = wred(inn * s);                                               \
        const int p_ = t_ & 1;                                                  \
        if (lane == 0) {                                                        \
            lds[p_][wid][0] = rP; lds[p_][wid][1] = rQ;                         \
            lds[p_][wid][2] = r0; lds[p_][wid][3] = r1;                         \
            lds[p_][wid][4] = rU; lds[p_][wid][5] = rV;                         \
        }                                                                       \
        __syncthreads();                                                        \
        float sP = 0.f, sQ = 0.f, sU = 0.f, sV = 0.f;                           \
        _Pragma("unroll")                                                       \
        for (int w = 0; w < 8; ++w) {                                           \
            sP += lds[p_][w][0]; sQ += lds[p_][w][1];                           \
            sU += lds[p_][w][4]; sV += lds[p_][w][5];                           \
        }                                                                       \
        if (r == 0) {                                                           \
            float o0 = 0.f, o1 = 0.f;                                           \
            _Pragma("unroll")                                                   \
            for (int w = 0; w < 8; ++w) { o0 += lds[p_][w][2]; o1 += lds[p_][w][3]; } \
            outp[(size_t)t_ * 2]     = o0;                                      \
            outp[(size_t)t_ * 2 + 1] = o1;                                      \
        }                                                                       \
        P = sP; Q = sQ; U = sU; V = sV;                                         \
    }

    for (int t = 0; t < TT; t += 3) {
        STEP(t + 0, n0, i1)
        STEP(t + 1, n1, i2)
        STEP(t + 2, n2, i0)
    }
#undef STEP
}

extern "C" void kernel_launch(void* const* d_in, const int* in_sizes, int n_in,
                              void* d_out, int out_size, void* d_ws, size_t ws_size,
                              hipStream_t stream) {
    (void)in_sizes; (void)n_in; (void)out_size; (void)d_ws; (void)ws_size;
    const float* input = (const float*)d_in[0];   // [B,T,513] f32
    const float* noise = (const float*)d_in[1];   // [B,T,512] f32
    const float* top   = (const float*)d_in[2];   // [2] f32
    const float* why   = (const float*)d_in[3];   // [2,512] f32
    float* out    = (float*)d_out;                // output [B,T,2] ...
    float* hstore = out + (size_t)BB * TT * 2;    // ... then hstore [B,T,512]
    rnn_fused<<<BB, 512, 0, stream>>>(input, noise, top, why, out, hstore);
}